// Round 1
// baseline (12687.827 us; speedup 1.0000x reference)
//
#include <hip/hip_runtime.h>
#include <float.h>

#define N_PTS 16384
#define M_PTS 4096
#define K_NN  16
#define CIN   64
#define COUT  64

// Exact f32 rounding to match numpy/jax: ((dx*dx + dy*dy) + dz*dz), no fma contraction.
__device__ __forceinline__ float dist2_exact(float ax, float ay, float az,
                                             float bx, float by, float bz) {
    float dx = __fsub_rn(ax, bx);
    float dy = __fsub_rn(ay, by);
    float dz = __fsub_rn(az, bz);
    return __fadd_rn(__fadd_rn(__fmul_rn(dx, dx), __fmul_rn(dy, dy)), __fmul_rn(dz, dz));
}

// ---------------------------------------------------------------------------
// Kernel 1: furthest point sampling. Single block (sequential dependence),
// 1024 threads, 16 points/thread in registers. Writes n_p (M,3) to out[0..12287]
// and n_o (=4096.0f) to out[798720].
// ---------------------------------------------------------------------------
__global__ __launch_bounds__(1024) void fps_kernel(const float* __restrict__ p,
                                                   float* __restrict__ out) {
    const int t = threadIdx.x;
    float px[16], py[16], pz[16], d2[16];
    __shared__ float s_val[16];
    __shared__ int   s_idx[16];
    __shared__ float s_q[3];

    const float q0x = p[0], q0y = p[1], q0z = p[2];
    float bv = -1.0f; int bi = 0;
#pragma unroll
    for (int u = 0; u < 16; ++u) {
        const int j = u * 1024 + t;
        px[u] = p[3 * j];
        py[u] = p[3 * j + 1];
        pz[u] = p[3 * j + 2];
        d2[u] = dist2_exact(px[u], py[u], pz[u], q0x, q0y, q0z);
        if (d2[u] > bv) { bv = d2[u]; bi = j; }   // ascending j -> first-index ties
    }
    if (t == 0) {
        out[0] = q0x; out[1] = q0y; out[2] = q0z;      // n_p[0] = p[0] (idx[0] = 0)
        out[12288 + 786432] = 4096.0f;                 // n_o scalar
    }

    const int lane = t & 63, wv = t >> 6;
    for (int i = 1; i < M_PTS; ++i) {
        // wave-level argmax (max value, min index on ties)
        float v = bv; int ix = bi;
#pragma unroll
        for (int off = 1; off < 64; off <<= 1) {
            float ov = __shfl_xor(v, off);
            int   oi = __shfl_xor(ix, off);
            if (ov > v || (ov == v && oi < ix)) { v = ov; ix = oi; }
        }
        if (lane == 0) { s_val[wv] = v; s_idx[wv] = ix; }
        __syncthreads();
        if (t == 0) {
            float vv = s_val[0]; int vi = s_idx[0];
#pragma unroll
            for (int w = 1; w < 16; ++w) {
                if (s_val[w] > vv || (s_val[w] == vv && s_idx[w] < vi)) {
                    vv = s_val[w]; vi = s_idx[w];
                }
            }
            const float qx = p[3 * vi], qy = p[3 * vi + 1], qz = p[3 * vi + 2];
            s_q[0] = qx; s_q[1] = qy; s_q[2] = qz;
            out[3 * i] = qx; out[3 * i + 1] = qy; out[3 * i + 2] = qz;
        }
        __syncthreads();
        const float qx = s_q[0], qy = s_q[1], qz = s_q[2];
        bv = -1.0f; bi = 0;
#pragma unroll
        for (int u = 0; u < 16; ++u) {
            const float d = dist2_exact(px[u], py[u], pz[u], qx, qy, qz);
            d2[u] = fminf(d2[u], d);
            if (d2[u] > bv) { bv = d2[u]; bi = u * 1024 + t; }
        }
    }
}

// ---------------------------------------------------------------------------
// Kernel 2: kNN (k=16) of each n_p among p. One wave per query, per-lane sorted
// top-16 in registers, lexicographic (d, idx) wave merge (matches top_k ties).
// Distance uses the reference's expanded form qq - 2*q.p + pp.
// ---------------------------------------------------------------------------
__global__ __launch_bounds__(256) void knn_kernel(const float* __restrict__ p,
                                                  const float* __restrict__ np_,
                                                  int* __restrict__ nn) {
    const int lane = threadIdx.x & 63;
    const int m = (blockIdx.x * 256 + threadIdx.x) >> 6;
    if (m >= M_PTS) return;

    const float qx = np_[3 * m], qy = np_[3 * m + 1], qz = np_[3 * m + 2];
    const float qq = __fadd_rn(__fadd_rn(__fmul_rn(qx, qx), __fmul_rn(qy, qy)),
                               __fmul_rn(qz, qz));
    float D[16]; int I[16];
#pragma unroll
    for (int s = 0; s < 16; ++s) { D[s] = FLT_MAX; I[s] = 0x7fffffff; }

    for (int c = 0; c < N_PTS / 64; ++c) {
        const int j = c * 64 + lane;
        const float px = p[3 * j], py = p[3 * j + 1], pz = p[3 * j + 2];
        const float pp = __fadd_rn(__fadd_rn(__fmul_rn(px, px), __fmul_rn(py, py)),
                                   __fmul_rn(pz, pz));
        const float qp = __fadd_rn(__fadd_rn(__fmul_rn(qx, px), __fmul_rn(qy, py)),
                                   __fmul_rn(qz, pz));
        const float d = __fadd_rn(__fsub_rn(qq, __fmul_rn(2.0f, qp)), pp);
        if (d < D[15]) {                 // equal d, later j -> discard (stable)
            D[15] = d; I[15] = j;
#pragma unroll
            for (int s = 15; s > 0; --s) {
                if (D[s] < D[s - 1]) {   // strict: stable on ties
                    float tf = D[s]; D[s] = D[s - 1]; D[s - 1] = tf;
                    int   ti = I[s]; I[s] = I[s - 1]; I[s - 1] = ti;
                }
            }
        }
    }

    // merge 64 sorted lists: 16 rounds of lexicographic wave-min extraction
    int myout = 0;
    for (int r = 0; r < 16; ++r) {
        float v = D[0]; int ix = I[0]; int bl = lane;
#pragma unroll
        for (int off = 1; off < 64; off <<= 1) {
            float ov = __shfl_xor(v, off);
            int   oi = __shfl_xor(ix, off);
            int   ol = __shfl_xor(bl, off);
            if (ov < v || (ov == v && oi < ix)) { v = ov; ix = oi; bl = ol; }
        }
        if (lane == bl) {                // winner pops its head
#pragma unroll
            for (int s = 0; s < 15; ++s) { D[s] = D[s + 1]; I[s] = I[s + 1]; }
            D[15] = FLT_MAX; I[15] = 0x7fffffff;
        }
        if (lane == r) myout = ix;
    }
    if (lane < K_NN) nn[m * K_NN + lane] = myout;
}

// ---------------------------------------------------------------------------
// Kernel 3: grouped VNLinearLeakyReLU + mean over nsample.
// One block per query m. W_feat/W_dir staged transposed in LDS; thread (o,i)
// accumulates over k. out layout (Cout,3,M): out[(o*3+i)*M + m].
// ---------------------------------------------------------------------------
__global__ __launch_bounds__(256) void vn_kernel(const float* __restrict__ x,
                                                 const float* __restrict__ Wf,
                                                 const float* __restrict__ Wd,
                                                 const int* __restrict__ nn,
                                                 float* __restrict__ out) {
    __shared__ float sWf[CIN * COUT];
    __shared__ float sWd[CIN * COUT];
    __shared__ float sg[CIN * 3];
    __shared__ float sq[COUT * 3];
    __shared__ float sd[COUT * 3];
    __shared__ float sf[COUT];

    const int m = blockIdx.x;
    const int tid = threadIdx.x;
    for (int u = tid; u < CIN * COUT; u += 256) {
        const int o = u >> 6, c = u & 63;
        sWf[c * 64 + o] = Wf[u];         // transpose: conflict-free reads later
        sWd[c * 64 + o] = Wd[u];
    }
    const int o = tid & 63, i = tid >> 6;
    const bool active = tid < 192;
    float acc = 0.0f;

    for (int k = 0; k < K_NN; ++k) {
        __syncthreads();                 // protect sg/sq/sd from previous iter
        const int j = nn[m * K_NN + k];
        if (tid < 192) sg[tid] = x[j * 192 + tid];
        __syncthreads();
        float qv = 0.0f, dv = 0.0f;
        if (active) {
#pragma unroll
            for (int c = 0; c < CIN; ++c) {
                const float g = sg[c * 3 + i];
                qv = fmaf(sWf[c * 64 + o], g, qv);
                dv = fmaf(sWd[c * 64 + o], g, dv);
            }
            sq[o * 3 + i] = qv;
            sd[o * 3 + i] = dv;
        }
        __syncthreads();
        if (tid < 64) {
            const float d0 = sd[tid * 3], d1 = sd[tid * 3 + 1], d2v = sd[tid * 3 + 2];
            const float q0 = sq[tid * 3], q1 = sq[tid * 3 + 1], q2 = sq[tid * 3 + 2];
            const float dot = q0 * d0 + q1 * d1 + q2 * d2v;
            const float dns = d0 * d0 + d1 * d1 + d2v * d2v + 1e-6f;
            // out = q - 0.8*(dot/dns)*d when dot<0 else q
            sf[tid] = (dot >= 0.0f) ? 0.0f : 0.8f * (dot / dns);
        }
        __syncthreads();
        if (active) acc += qv - sf[o] * dv;
    }
    if (active) out[(o * 3 + i) * M_PTS + m] = acc * 0.0625f;  // mean over 16
}

// ---------------------------------------------------------------------------
extern "C" void kernel_launch(void* const* d_in, const int* in_sizes, int n_in,
                              void* d_out, int out_size, void* d_ws, size_t ws_size,
                              hipStream_t stream) {
    const float* p  = (const float*)d_in[0];
    const float* x  = (const float*)d_in[1];
    const float* Wf = (const float*)d_in[2];
    const float* Wd = (const float*)d_in[3];
    float* out = (float*)d_out;
    int* nn = (int*)d_ws;                       // 4096*16 ints = 256 KiB scratch

    fps_kernel<<<1, 1024, 0, stream>>>(p, out);
    knn_kernel<<<M_PTS / 4, 256, 0, stream>>>(p, out, nn);
    vn_kernel<<<M_PTS, 256, 0, stream>>>(x, Wf, Wd, nn, out + 12288);
}

// Round 2
// 7473.013 us; speedup vs baseline: 1.6978x; 1.6978x over previous
//
#include <hip/hip_runtime.h>
#include <float.h>

#define N_PTS 16384
#define M_PTS 4096
#define K_NN  16
#define CIN   64
#define COUT  64

// Exact f32 rounding to match numpy/jax: ((dx*dx + dy*dy) + dz*dz), no fma contraction.
__device__ __forceinline__ float dist2_exact(float ax, float ay, float az,
                                             float bx, float by, float bz) {
    float dx = __fsub_rn(ax, bx);
    float dy = __fsub_rn(ay, by);
    float dz = __fsub_rn(az, bz);
    return __fadd_rn(__fadd_rn(__fmul_rn(dx, dx), __fmul_rn(dy, dy)), __fmul_rn(dz, dz));
}

// ---- DPP wave-64 reductions (max/min are idempotent -> full masks are safe) ----
// Canonical GCN sequence: row_shr 1,2,4,8 then row_bcast:15, row_bcast:31 -> lane 63.
template <int CTRL>
__device__ __forceinline__ float dpp_fmax_step(float x) {
    int xi = __float_as_int(x);
    int yi = __builtin_amdgcn_update_dpp(xi, xi, CTRL, 0xf, 0xf, false);
    return fmaxf(x, __int_as_float(yi));
}
template <int CTRL>
__device__ __forceinline__ unsigned dpp_umin_step(unsigned x) {
    int xi = (int)x;
    unsigned y = (unsigned)__builtin_amdgcn_update_dpp(xi, xi, CTRL, 0xf, 0xf, false);
    return y < x ? y : x;
}
template <int CTRL>
__device__ __forceinline__ unsigned long long dpp_u64max_step(unsigned long long x) {
    int lo = (int)(unsigned)x;
    int hi = (int)(unsigned)(x >> 32);
    unsigned olo = (unsigned)__builtin_amdgcn_update_dpp(lo, lo, CTRL, 0xf, 0xf, false);
    unsigned ohi = (unsigned)__builtin_amdgcn_update_dpp(hi, hi, CTRL, 0xf, 0xf, false);
    unsigned long long o = ((unsigned long long)ohi << 32) | (unsigned long long)olo;
    return o > x ? o : x;
}

// Wave argmax: max value, min index on ties. Results returned as wave-uniform (SGPR).
__device__ __forceinline__ void wave_argmax(float bv, unsigned bi,
                                            float& vmax, unsigned& imin) {
    float x = bv;
    x = dpp_fmax_step<0x111>(x);   // row_shr:1
    x = dpp_fmax_step<0x112>(x);   // row_shr:2
    x = dpp_fmax_step<0x114>(x);   // row_shr:4
    x = dpp_fmax_step<0x118>(x);   // row_shr:8
    x = dpp_fmax_step<0x142>(x);   // row_bcast:15
    x = dpp_fmax_step<0x143>(x);   // row_bcast:31
    int vm = __builtin_amdgcn_readlane(__float_as_int(x), 63);
    vmax = __int_as_float(vm);     // wave-uniform
    unsigned cand = (bv == vmax) ? bi : 0xffffffffu;
    cand = dpp_umin_step<0x111>(cand);
    cand = dpp_umin_step<0x112>(cand);
    cand = dpp_umin_step<0x114>(cand);
    cand = dpp_umin_step<0x118>(cand);
    cand = dpp_umin_step<0x142>(cand);
    cand = dpp_umin_step<0x143>(cand);
    imin = (unsigned)__builtin_amdgcn_readlane((int)cand, 63);
}

// ---------------------------------------------------------------------------
// Kernel 1: furthest point sampling. Single block, 1024 threads, 16 pts/thread
// held in REGISTERS (launch_bounds(1024,4) -> 128-VGPR budget, no scratch).
// One barrier per iteration; parity-double-buffered packed keys in LDS.
// ---------------------------------------------------------------------------
__global__ __launch_bounds__(1024, 4) void fps_kernel(const float* __restrict__ p,
                                                      float* __restrict__ out) {
    const int t = threadIdx.x;
    const int lane = t & 63, wv = t >> 6;
    __shared__ unsigned long long s_pack[2][16];

    float px[16], py[16], pz[16], d2[16];
    const float q0x = p[0], q0y = p[1], q0z = p[2];
    float bv = -1.0f; unsigned bi = 0;
#pragma unroll
    for (int u = 0; u < 16; ++u) {
        const int j = u * 1024 + t;
        px[u] = p[3 * j];
        py[u] = p[3 * j + 1];
        pz[u] = p[3 * j + 2];
        d2[u] = dist2_exact(px[u], py[u], pz[u], q0x, q0y, q0z);
        if (d2[u] > bv) { bv = d2[u]; bi = (unsigned)j; }   // ascending j: first-index ties
    }
    if (t == 0) {
        out[0] = q0x; out[1] = q0y; out[2] = q0z;      // n_p[0] = p[0]
        out[12288 + 786432] = 4096.0f;                 // n_o scalar
    }

    for (int i = 1; i < M_PTS; ++i) {
        // per-wave argmax, then post packed key (max d2, min index on ties)
        float vmax; unsigned imin;
        wave_argmax(bv, bi, vmax, imin);
        if (lane == 63) {
            s_pack[i & 1][wv] =
                ((unsigned long long)__float_as_uint(vmax) << 32) |
                (unsigned long long)(~imin);           // ~idx: bigger key = smaller idx
        }
        __syncthreads();   // single barrier per iteration (parity buffers make it safe)

        // cross-wave reduce: lanes read the 16 keys (lane&15 -> conflict-free b64,
        // 4x broadcast), 4-step u64 DPP max within each 16-lane row.
        unsigned long long key = s_pack[i & 1][lane & 15];
        key = dpp_u64max_step<0x111>(key);
        key = dpp_u64max_step<0x112>(key);
        key = dpp_u64max_step<0x114>(key);
        key = dpp_u64max_step<0x118>(key);
        // every row's lane 15 (so also lane 63) now holds the global max key
        const unsigned klo = (unsigned)__builtin_amdgcn_readlane((int)(unsigned)key, 63);
        const int vi = (int)(~klo);                    // SGPR-uniform picked index

        const float qx = p[3 * vi], qy = p[3 * vi + 1], qz = p[3 * vi + 2];
        if (t == 0) { out[3 * i] = qx; out[3 * i + 1] = qy; out[3 * i + 2] = qz; }

        bv = -1.0f; bi = 0;
#pragma unroll
        for (int u = 0; u < 16; ++u) {
            const float d = dist2_exact(px[u], py[u], pz[u], qx, qy, qz);
            d2[u] = fminf(d2[u], d);
            if (d2[u] > bv) { bv = d2[u]; bi = (unsigned)(u * 1024 + t); }
        }
    }
}

// ---------------------------------------------------------------------------
// Kernel 2: kNN (k=16) of each n_p among p. One wave per query, per-lane sorted
// top-16 in registers, lexicographic (d, idx) wave merge (matches top_k ties).
// ---------------------------------------------------------------------------
__global__ __launch_bounds__(256) void knn_kernel(const float* __restrict__ p,
                                                  const float* __restrict__ np_,
                                                  int* __restrict__ nn) {
    const int lane = threadIdx.x & 63;
    const int m = (blockIdx.x * 256 + threadIdx.x) >> 6;
    if (m >= M_PTS) return;

    const float qx = np_[3 * m], qy = np_[3 * m + 1], qz = np_[3 * m + 2];
    const float qq = __fadd_rn(__fadd_rn(__fmul_rn(qx, qx), __fmul_rn(qy, qy)),
                               __fmul_rn(qz, qz));
    float D[16]; int I[16];
#pragma unroll
    for (int s = 0; s < 16; ++s) { D[s] = FLT_MAX; I[s] = 0x7fffffff; }

    for (int c = 0; c < N_PTS / 64; ++c) {
        const int j = c * 64 + lane;
        const float px = p[3 * j], py = p[3 * j + 1], pz = p[3 * j + 2];
        const float pp = __fadd_rn(__fadd_rn(__fmul_rn(px, px), __fmul_rn(py, py)),
                                   __fmul_rn(pz, pz));
        const float qp = __fadd_rn(__fadd_rn(__fmul_rn(qx, px), __fmul_rn(qy, py)),
                                   __fmul_rn(qz, pz));
        const float d = __fadd_rn(__fsub_rn(qq, __fmul_rn(2.0f, qp)), pp);
        if (d < D[15]) {
            D[15] = d; I[15] = j;
#pragma unroll
            for (int s = 15; s > 0; --s) {
                if (D[s] < D[s - 1]) {
                    float tf = D[s]; D[s] = D[s - 1]; D[s - 1] = tf;
                    int   ti = I[s]; I[s] = I[s - 1]; I[s - 1] = ti;
                }
            }
        }
    }

    int myout = 0;
    for (int r = 0; r < 16; ++r) {
        float v = D[0]; int ix = I[0]; int bl = lane;
#pragma unroll
        for (int off = 1; off < 64; off <<= 1) {
            float ov = __shfl_xor(v, off);
            int   oi = __shfl_xor(ix, off);
            int   ol = __shfl_xor(bl, off);
            if (ov < v || (ov == v && oi < ix)) { v = ov; ix = oi; bl = ol; }
        }
        if (lane == bl) {
#pragma unroll
            for (int s = 0; s < 15; ++s) { D[s] = D[s + 1]; I[s] = I[s + 1]; }
            D[15] = FLT_MAX; I[15] = 0x7fffffff;
        }
        if (lane == r) myout = ix;
    }
    if (lane < K_NN) nn[m * K_NN + lane] = myout;
}

// ---------------------------------------------------------------------------
// Kernel 3: grouped VNLinearLeakyReLU + mean over nsample.
// One block per query m. W_feat/W_dir staged transposed in LDS; thread (o,i)
// accumulates over k. out layout (Cout,3,M): out[(o*3+i)*M + m].
// ---------------------------------------------------------------------------
__global__ __launch_bounds__(256) void vn_kernel(const float* __restrict__ x,
                                                 const float* __restrict__ Wf,
                                                 const float* __restrict__ Wd,
                                                 const int* __restrict__ nn,
                                                 float* __restrict__ out) {
    __shared__ float sWf[CIN * COUT];
    __shared__ float sWd[CIN * COUT];
    __shared__ float sg[CIN * 3];
    __shared__ float sq[COUT * 3];
    __shared__ float sd[COUT * 3];
    __shared__ float sf[COUT];

    const int m = blockIdx.x;
    const int tid = threadIdx.x;
    for (int u = tid; u < CIN * COUT; u += 256) {
        const int o = u >> 6, c = u & 63;
        sWf[c * 64 + o] = Wf[u];
        sWd[c * 64 + o] = Wd[u];
    }
    const int o = tid & 63, i = tid >> 6;
    const bool active = tid < 192;
    float acc = 0.0f;

    for (int k = 0; k < K_NN; ++k) {
        __syncthreads();
        const int j = nn[m * K_NN + k];
        if (tid < 192) sg[tid] = x[j * 192 + tid];
        __syncthreads();
        float qv = 0.0f, dv = 0.0f;
        if (active) {
#pragma unroll
            for (int c = 0; c < CIN; ++c) {
                const float g = sg[c * 3 + i];
                qv = fmaf(sWf[c * 64 + o], g, qv);
                dv = fmaf(sWd[c * 64 + o], g, dv);
            }
            sq[o * 3 + i] = qv;
            sd[o * 3 + i] = dv;
        }
        __syncthreads();
        if (tid < 64) {
            const float d0 = sd[tid * 3], d1 = sd[tid * 3 + 1], d2v = sd[tid * 3 + 2];
            const float q0 = sq[tid * 3], q1 = sq[tid * 3 + 1], q2 = sq[tid * 3 + 2];
            const float dot = q0 * d0 + q1 * d1 + q2 * d2v;
            const float dns = d0 * d0 + d1 * d1 + d2v * d2v + 1e-6f;
            sf[tid] = (dot >= 0.0f) ? 0.0f : 0.8f * (dot / dns);
        }
        __syncthreads();
        if (active) acc += qv - sf[o] * dv;
    }
    if (active) out[(o * 3 + i) * M_PTS + m] = acc * 0.0625f;
}

// ---------------------------------------------------------------------------
extern "C" void kernel_launch(void* const* d_in, const int* in_sizes, int n_in,
                              void* d_out, int out_size, void* d_ws, size_t ws_size,
                              hipStream_t stream) {
    const float* p  = (const float*)d_in[0];
    const float* x  = (const float*)d_in[1];
    const float* Wf = (const float*)d_in[2];
    const float* Wd = (const float*)d_in[3];
    float* out = (float*)d_out;
    int* nn = (int*)d_ws;

    fps_kernel<<<1, 1024, 0, stream>>>(p, out);
    knn_kernel<<<M_PTS / 4, 256, 0, stream>>>(p, out, nn);
    vn_kernel<<<M_PTS, 256, 0, stream>>>(x, Wf, Wd, nn, out + 12288);
}